// Round 17
// baseline (173.660 us; speedup 1.0000x reference)
//
#include <hip/hip_runtime.h>
#include <cstdint>
#include <cfloat>
#include <math.h>

// Problem constants (match reference)
#define BB 16
#define SS 64
#define VV 50257
#define PP 64

#define NT 512          // threads per block (8 waves; 4 blocks/CU -> 32 waves/CU)
#define NBLKC 512       // compute blocks; block g handles rows g and g+512 (same s)
#define GRID 1024       // + 512 fill blocks (producer/consumer split)
#define BINS 2048       // key histogram bins (top 11 bits of ordered key)
#define CAP 1536        // candidate buffer capacity
#define BMW 1572        // bitmap words: ceil(50257/32)=1571 (+1 pad)
#define KCAP 128        // kept (top-k survivors) capacity
#define BCAP 512        // kth-bin member list capacity
#define TRAW 6.0f       // raw-domain candidate threshold (= 7.5 scaled * 0.8)
#define MAGIC 0x5AC0FFEEu

// RULES LEARNED:
//  - no atomic/shfl in stream address path (R11); one crew owns one whole
//    row-stream (R12/R15 WRITE-inflation gremlin); in-block schedule variants
//    all plateau at ~90us because identical blocks run in device-wide
//    lockstep (read-phases and write-phases never overlap) -> this round
//    splits blocks into producer/consumer to force R/W overlap.

typedef float f32x4 __attribute__((ext_vector_type(4)));

// monotone float->uint key (increasing)
__device__ __forceinline__ uint32_t fkey(float f) {
    uint32_t u = __float_as_uint(f);
    return u ^ ((uint32_t)((int32_t)u >> 31) | 0x80000000u);
}
__device__ __forceinline__ float key2f(uint32_t u) {
    uint32_t b = (u & 0x80000000u) ? (u ^ 0x80000000u) : ~u;
    return __uint_as_float(b);
}

__global__ __launch_bounds__(NT)
void sch_kernel(const float* __restrict__ logits,
                const int* __restrict__ prev,
                float* __restrict__ out,
                unsigned int* __restrict__ ws)
{
    // ws layout (uint words): flag[1024] | rc[1024] | kp[1024] | ki[1024*64] | kof[1024*64]
    unsigned int* wflag = ws;
    unsigned int* wrc   = ws + 1024;
    unsigned int* wkp   = ws + 2048;
    unsigned int* wki   = ws + 3072;
    unsigned int* wkof  = ws + 3072 + 1024 * 64;

    const int tid = threadIdx.x;

    // ============================ FILL blocks ============================
    if (blockIdx.x >= NBLKC) {
        const int f = blockIdx.x - NBLKC;
        #pragma unroll 1
        for (int half = 0; half < 2; ++half) {
            const int rr = f + half * NBLKC;          // row f then f+512
            float* orow = out + (size_t)rr * VV;
            if (tid == 0) {
                while (atomicAdd(&wflag[rr], 0u) != MAGIC)
                    __builtin_amdgcn_s_sleep(8);
                __threadfence();
            }
            __syncthreads();
            const int   kp = (int)atomicAdd(&wkp[rr], 0u);
            const float rc = __uint_as_float(atomicAdd(&wrc[rr], 0u));
            int ki_t = 0; float ko_t = 0.f;
            if (tid < kp) {
                ki_t = (int)atomicAdd(&wki[rr * 64 + tid], 0u);
                ko_t = __uint_as_float(atomicAdd(&wkof[rr * 64 + tid], 0u));
            }
            const int omis   = (int)(((size_t)orow >> 2) & 3);
            const int ohead  = (4 - omis) & 3;
            const int onq    = (VV - ohead) >> 2;
            const int ottail = ohead + (onq << 2);
            f32x4* o4 = reinterpret_cast<f32x4*>(orow + ohead);
            f32x4 rc4; rc4.x = rc; rc4.y = rc; rc4.z = rc; rc4.w = rc;
            for (int t = tid; t < ohead; t += NT)
                __builtin_nontemporal_store(rc, &orow[t]);
            for (int q = tid; q < onq; q += NT)
                __builtin_nontemporal_store(rc4, &o4[q]);
            for (int t = ottail + tid; t < VV; t += NT)
                __builtin_nontemporal_store(rc, &orow[t]);
            __syncthreads();                           // drain fills (vmcnt 0)
            if (tid < kp) orow[ki_t] = ko_t;           // scatter wins
            if (tid == 0) atomicExch(&wflag[rr], 0u);  // reset for next replay
            __syncthreads();
        }
        return;
    }

    // ============================ COMPUTE blocks ============================
    const int g   = blockIdx.x;            // 0..511
    const int rA  = g;
    const int rB  = g + NBLKC;
    const int s   = g % SS;                // rA%SS == rB%SS (512 % 64 == 0)
    const int bA  = rA / SS;
    const int bB  = rB / SS;
    const float* rowA = logits + (size_t)rA * VV;
    const float* rowB = logits + (size_t)rB * VV;

    __shared__ uint32_t s_bm[BMW];
    __shared__ float    s_cv[CAP];    // candidates, PRE-TEMPERATURE domain
    __shared__ int      s_ci[CAP];
    __shared__ uint32_t s_hist[BINS];
    __shared__ uint32_t s_scan[16];   // 8 wave totals + 8 prefixes
    __shared__ int      s_ptok[PP];
    __shared__ int      s_pneg[PP];   // all_neg flag (same for both rows: same s)
    __shared__ float    s_prawA[PP];
    __shared__ float    s_prawB[PP];
    __shared__ float    s_ppenA[PP];
    __shared__ float    s_ppenB[PP];
    __shared__ float    s_binv[BCAP];
    __shared__ double   s_v64[KCAP];
    __shared__ double   s_e64[KCAP];
    __shared__ int      s_ki[KCAP];
    __shared__ float    s_kof[KCAP];
    __shared__ int    s_cnt, s_cntinv, s_b50, s_need, s_cntb, s_k50, s_kp, s_Kk;
    __shared__ float  s_kth, s_rc;
    __shared__ double s_lse;

    // ---------------- phase 0: penalty setup, ONCE for both rows ----------------
    for (int i = tid; i < BMW; i += NT) s_bm[i] = 0u;
    if (tid < PP) s_pneg[tid] = 1;
    if (tid == 0) { s_cnt = 0; s_cntinv = 0; }
    __syncthreads();
    for (int pair = tid; pair < PP * BB; pair += NT) {
        int ti = pair & (PP - 1);
        int b2 = pair >> 6;
        int tok = prev[s * PP + ti];
        float gg = logits[((size_t)b2 * SS + s) * (size_t)VV + tok];
        if (gg >= 0.f) atomicAnd(&s_pneg[ti], 0);
        if (b2 == 0)  s_ptok[ti]  = tok;
        if (b2 == bA) s_prawA[ti] = gg;
        if (b2 == bB) s_prawB[ti] = gg;
    }
    __syncthreads();
    if (tid < PP) {
        int neg = s_pneg[tid];
        float ga = s_prawA[tid], gb = s_prawB[tid];
        s_ppenA[tid] = neg ? (ga * 1.2f) : (ga / 1.2f);
        s_ppenB[tid] = neg ? (gb * 1.2f) : (gb / 1.2f);
        int tok = s_ptok[tid];
        atomicOr(&s_bm[tok >> 5], 1u << (tok & 31));
    }
    __syncthreads();

    // ---------------- helpers ----------------
    auto kbit = [&](int t) -> uint32_t {
        return (s_bm[t >> 5] >> (t & 31)) & 1u;
    };
    auto addRaw = [&](int t, float raw) {
        if (raw >= TRAW) {
            int pos = atomicAdd(&s_cnt, 1);
            if (pos < CAP) { s_cv[pos] = raw; s_ci[pos] = t; }
        }
    };
    // full-block hot read stream, 4-deep unrolled, no LDS on fast path
    auto streamFast = [&](const float* row_) {
        const int mis   = (int)(((size_t)row_ >> 2) & 3);
        const int head  = (4 - mis) & 3;
        const int nq    = (VV - head) >> 2;
        const int ttail = head + (nq << 2);
        const float4* p4 = reinterpret_cast<const float4*>(row_ + head);
        for (int t = tid; t < head; t += NT) addRaw(t, row_[t]);
        int base = 0;
        for (; base + 4 * NT <= nq; base += 4 * NT) {
            float4 f[4];
            #pragma unroll
            for (int u = 0; u < 4; ++u) f[u] = p4[base + tid + u * NT];
            #pragma unroll
            for (int u = 0; u < 4; ++u) {
                int t = head + ((base + tid + u * NT) << 2);
                addRaw(t + 0, f[u].x);
                addRaw(t + 1, f[u].y);
                addRaw(t + 2, f[u].z);
                addRaw(t + 3, f[u].w);
            }
        }
        for (int q = base + tid; q < nq; q += NT) {
            float4 f = p4[q];
            int t = head + (q << 2);
            addRaw(t + 0, f.x); addRaw(t + 1, f.y);
            addRaw(t + 2, f.z); addRaw(t + 3, f.w);
        }
        for (int t = ttail + tid; t < VV; t += NT) addRaw(t, row_[t]);
    };
    // full path (rare fallback): per-element penalty substitution, pre-temp domain
    auto procFull = [&](int t, float raw, bool doHist, float thr, const float* ppenS) {
        float v = raw;
        if (kbit(t)) {
            #pragma unroll 1
            for (int j = 0; j < PP; ++j)
                if (s_ptok[j] == t) { v = ppenS[j]; break; }
        }
        if (!doHist) {
            if (v >= thr) {
                int pos = atomicAdd(&s_cnt, 1);
                if (pos < CAP) { s_cv[pos] = v; s_ci[pos] = t; }
            }
        } else {
            atomicAdd(&s_hist[fkey(v) >> 21], 1u);
        }
    };
    auto streamFull = [&](bool doHist, float thr, const float* row_, const float* ppenS) {
        const int mis   = (int)(((size_t)row_ >> 2) & 3);
        const int head  = (4 - mis) & 3;
        const int nq    = (VV - head) >> 2;
        const int ttail = head + (nq << 2);
        const float4* p4 = reinterpret_cast<const float4*>(row_ + head);
        for (int t = tid; t < head; t += NT) procFull(t, row_[t], doHist, thr, ppenS);
        for (int q = tid; q < nq; q += NT) {
            float4 f = p4[q];
            int t = head + (q << 2);
            procFull(t + 0, f.x, doHist, thr, ppenS);
            procFull(t + 1, f.y, doHist, thr, ppenS);
            procFull(t + 2, f.z, doHist, thr, ppenS);
            procFull(t + 3, f.w, doHist, thr, ppenS);
        }
        for (int t = ttail + tid; t < VV; t += NT) procFull(t, row_[t], doHist, thr, ppenS);
    };
    // suffix "find bin crossing target from top" (full-block, NT=512)
    auto findB50 = [&](int target) {
        __syncthreads();                     // histogram complete
        const int per = BINS / NT;           // 4 bins per thread
        int base = tid * per;
        uint32_t loc = 0;
        #pragma unroll
        for (int k2 = 0; k2 < per; ++k2) loc += s_hist[base + k2];
        uint32_t incl = loc;
        #pragma unroll
        for (int off = 1; off < 64; off <<= 1) {
            uint32_t u = (uint32_t)__shfl_up((int)incl, off, 64);
            if ((tid & 63) >= off) incl += u;
        }
        int wid = tid >> 6;                  // 0..7
        if ((tid & 63) == 63) s_scan[wid] = incl;
        __syncthreads();
        if (tid < 8) {
            uint32_t p = 0;
            for (int w = 0; w < tid; ++w) p += s_scan[w];
            s_scan[8 + tid] = p;
        }
        __syncthreads();
        uint32_t pre_incl = s_scan[8 + wid] + incl;
        uint32_t total    = s_scan[8 + 7] + s_scan[7];
        uint32_t run = total - pre_incl;
        for (int k2 = per - 1; k2 >= 0; --k2) {
            uint32_t h = s_hist[base + k2];
            uint32_t run2 = run + h;
            if (run < (uint32_t)target && run2 >= (uint32_t)target) {
                s_b50 = base + k2;
                s_need = target - (int)run;
            }
            run = run2;
        }
        __syncthreads();
    };
    auto doFallback = [&](const float* row_, const float* ppenS) {
        for (int i = tid; i < BINS; i += NT) s_hist[i] = 0u;
        __syncthreads();
        streamFull(true, 0.f, row_, ppenS);
        findB50(50);
        float thrF = key2f((uint32_t)s_b50 << 21);
        if (tid == 0) s_cnt = 0;
        __syncthreads();
        streamFull(false, thrF, row_, ppenS);
        __syncthreads();
    };
    auto computeKth = [&]() {
        for (int i = tid; i < BINS; i += NT) s_hist[i] = 0u;
        if (tid == 0) { s_cntb = 0; s_kth = -FLT_MAX; }
        __syncthreads();
        int cc = min(s_cnt, CAP);
        for (int i = tid; i < cc; i += NT)
            atomicAdd(&s_hist[fkey(s_cv[i]) >> 21], 1u);
        findB50(50);
        int b50 = s_b50, need = s_need;
        for (int i = tid; i < cc; i += NT) {
            if ((int)(fkey(s_cv[i]) >> 21) == b50) {
                int p = atomicAdd(&s_cntb, 1);
                if (p < BCAP) s_binv[p] = s_cv[i];
            }
        }
        __syncthreads();
        int cb = min(s_cntb, BCAP);
        for (int i = tid; i < cb; i += NT) {    // rank-count (grid-stride)
            float vi = s_binv[i];
            int gt = 0, ge = 0;
            for (int j = 0; j < cb; ++j) {
                float vj = s_binv[j];
                gt += (vj > vi);
                ge += (vj >= vi);
            }
            if (gt < need && ge >= need) s_kth = vi;   // benign race: same value
        }
        __syncthreads();
    };
    // mid phases, full-block. Decision arithmetic identical to R3+ (absmax 0).
    auto midPhases = [&](const float* row_, const float* prawS, const float* ppenS) {
        const int cntRaw = min(s_cnt, CAP);
        for (int i = tid; i < cntRaw; i += NT) {   // invalidate penalized raw entries
            if (kbit(s_ci[i])) {
                s_cv[i] = -FLT_MAX;
                atomicAdd(&s_cntinv, 1);
            }
        }
        __syncthreads();
        if (tid < PP) {                            // inject pen values (dedupe)
            int tok = s_ptok[tid];
            bool first = true;
            for (int j = 0; j < tid; ++j)
                if (s_ptok[j] == tok) { first = false; break; }
            if (first) {
                int pos = atomicAdd(&s_cnt, 1);
                if (pos < CAP) { s_cv[pos] = ppenS[tid]; s_ci[pos] = tok; }
            }
        }
        __syncthreads();
        bool fellback = false;
        {
            bool okc = (s_cnt <= CAP) && ((cntRaw - s_cntinv) >= 50);
            if (!okc) { doFallback(row_, ppenS); fellback = true; }
        }
        computeKth();
        if (!fellback && (s_kth - 1e-4f < TRAW)) { // margin guard: superset unproven
            doFallback(row_, ppenS);
            computeKth();
        }
        if (tid == 0) s_k50 = 0;
        __syncthreads();
        const float gthr = s_kth - 1e-4f;
        const int cntc = min(s_cnt, CAP);
        for (int i = tid; i < cntc; i += NT) {
            if (s_cv[i] >= gthr) {
                int p = atomicAdd(&s_k50, 1);
                if (p < KCAP) {
                    int tok = s_ci[i];
                    double v64;
                    if (kbit(tok)) {               // penalized: exact f64 recompute
                        int pj = 0;
                        #pragma unroll 1
                        for (int j = 0; j < PP; ++j)
                            if (s_ptok[j] == tok) { pj = j; break; }
                        double gd = (double)prawS[pj];
                        double pen = s_pneg[pj] ? (gd * 1.2) : (gd / 1.2);
                        v64 = pen / 0.8;
                    } else {
                        v64 = (double)s_cv[i] / 0.8;
                    }
                    s_v64[p] = v64;
                    s_ki[p]  = tok;
                }
            }
        }
        __syncthreads();
        const int k50c = min(s_k50, KCAP);
        for (int i = k50c + tid; i < KCAP; i += NT) {
            s_v64[i] = -1e300;
            s_ki[i]  = (1 << 30) + i;
        }
        __syncthreads();
        // single-wave register bitonic sort (128 slots, identical comparator)
        if (tid < 64) {
            int l = tid;
            double v0 = s_v64[l],    v1 = s_v64[l + 64];
            int    i0 = s_ki[l],     i1 = s_ki[l + 64];
            for (int k = 2; k <= KCAP; k <<= 1) {
                for (int j = k >> 1; j > 0; j >>= 1) {
                    if (j >= 64) {
                        bool before = (v0 > v1) || (v0 == v1 && i0 < i1);
                        if (!before) {
                            double tv = v0; v0 = v1; v1 = tv;
                            int    ti = i0; i0 = i1; i1 = ti;
                        }
                    } else {
                        double nv0 = __shfl_xor(v0, j, 64);
                        double nv1 = __shfl_xor(v1, j, 64);
                        int    ni0 = __shfl_xor(i0, j, 64);
                        int    ni1 = __shfl_xor(i1, j, 64);
                        bool lower = ((l & j) == 0);
                        bool up0 = ((l & k) == 0);
                        bool up1 = (((l + 64) & k) == 0);
                        bool bm0 = (v0 > nv0) || (v0 == nv0 && i0 < ni0);
                        bool bm1 = (v1 > nv1) || (v1 == nv1 && i1 < ni1);
                        bool keep0 = lower ? (up0 == bm0) : (up0 != bm0);
                        bool keep1 = lower ? (up1 == bm1) : (up1 != bm1);
                        if (!keep0) { v0 = nv0; i0 = ni0; }
                        if (!keep1) { v1 = nv1; i1 = ni1; }
                    }
                }
            }
            s_v64[l] = v0; s_v64[l + 64] = v1;
            s_ki[l]  = i0; s_ki[l + 64]  = i1;
        }
        __syncthreads();
        if (tid == 0) {
            int kk = k50c;
            int Kkept;
            if (kk <= 50) Kkept = kk;
            else {
                double kth64 = s_v64[49];
                Kkept = 50;
                while (Kkept < kk && s_v64[Kkept] == kth64) ++Kkept;
            }
            s_Kk = Kkept;
        }
        __syncthreads();
        const int Kk = s_Kk;
        const double mx = s_v64[0];
        if (tid < Kk) s_e64[tid] = exp(s_v64[tid] - mx);
        __syncthreads();
        if (tid == 0) {
            double D = 0.0;                    // same serial order as reference
            #pragma unroll 1
            for (int i = 0; i < Kk; ++i) D += s_e64[i];
            double c = 0.0;
            int Kp = 0;
            #pragma unroll 1
            for (int i = 0; i < Kk; ++i) {
                bool keep = (i == 0) || (c <= 0.9);
                c += s_e64[i] / D;
                if (keep) Kp = i + 1; else break;
            }
            double D2 = 0.0;
            #pragma unroll 1
            for (int i = 0; i < Kp; ++i) D2 += s_e64[i];
            double lse = log(D2);
            s_lse = lse;
            s_rc = (float)((-1e9 - mx) - lse);
            s_kp = Kp;
        }
        __syncthreads();
        if (tid < s_kp) s_kof[tid] = (float)((s_v64[tid] - mx) - s_lse);
        __syncthreads();
    };
    // publish row results to ws; release with device fence + MAGIC flag
    auto publish = [&](int r) {
        if (tid < s_kp) {
            wki[r * 64 + tid]  = (unsigned int)s_ki[tid];
            wkof[r * 64 + tid] = __float_as_uint(s_kof[tid]);
        }
        if (tid == 0) {
            wrc[r] = __float_as_uint(s_rc);
            wkp[r] = (unsigned int)s_kp;
        }
        __syncthreads();                       // payload stores drained (vmcnt 0)
        if (tid == 0) {
            __threadfence();                   // device-scope release
            atomicExch(&wflag[r], MAGIC);
        }
    };

    // ============================ compute schedule ============================
    streamFast(rowA);
    __syncthreads();
    midPhases(rowA, s_prawA, s_ppenA);
    publish(rA);
    if (tid == 0) { s_cnt = 0; s_cntinv = 0; }
    __syncthreads();
    streamFast(rowB);
    __syncthreads();
    midPhases(rowB, s_prawB, s_ppenB);
    publish(rB);
}

extern "C" void kernel_launch(void* const* d_in, const int* in_sizes, int n_in,
                              void* d_out, int out_size, void* d_ws, size_t ws_size,
                              hipStream_t stream) {
    const float* logits = (const float*)d_in[0];
    const int*   prev   = (const int*)d_in[1];
    float*       out    = (float*)d_out;
    unsigned int* ws    = (unsigned int*)d_ws;
    dim3 grid(GRID), block(NT);
    hipLaunchKernelGGL(sch_kernel, grid, block, 0, stream, logits, prev, out, ws);
}

// Round 18
// 106.940 us; speedup vs baseline: 1.6239x; 1.6239x over previous
//
#include <hip/hip_runtime.h>
#include <cstdint>
#include <cfloat>
#include <math.h>

// Problem constants (match reference)
#define BB 16
#define SS 64
#define VV 50257
#define PP 64

#define NT 1024         // threads per block (16 waves; 2 blocks/CU -> 32 waves/CU)
#define HNT 512         // half-block (waves 0-7) running the mid phases
#define NBLK 512        // block g handles rows g and g+512 (same s, same prev!)
#define BINS 2048       // key histogram bins (top 11 bits of ordered key)
#define CAP 1536        // candidate buffer capacity
#define BMW 1572        // bitmap words: ceil(50257/32)=1571 (+1 pad)
#define KCAP 128        // kept (top-k survivors) capacity
#define BCAP 512        // kth-bin member list capacity
#define TRAW 6.0f       // raw-domain candidate threshold (= 7.5 scaled * 0.8)

// RULES LEARNED:
//  - no atomic/shfl in the stream address path (R11: kills MLP)
//  - only the 8-wave/512-thread crew geometry streams cleanly (R12/R15)
//  - block producer/consumer specialization idles half the device (R17)
//  - R18 lever: fill stores `nt sc1` = no-allocate at Infinity Cache, so the
//    206MB logits stay L3-resident across replays (FETCH 104MB -> small)

typedef float f32x4 __attribute__((ext_vector_type(4)));

// monotone float->uint key (increasing)
__device__ __forceinline__ uint32_t fkey(float f) {
    uint32_t u = __float_as_uint(f);
    return u ^ ((uint32_t)((int32_t)u >> 31) | 0x80000000u);
}
__device__ __forceinline__ float key2f(uint32_t u) {
    uint32_t b = (u & 0x80000000u) ? (u ^ 0x80000000u) : ~u;
    return __uint_as_float(b);
}

__device__ __forceinline__ void ntStore4(float* p, f32x4 v) {
    asm volatile("global_store_dwordx4 %0, %1, off nt sc1"
                 :: "v"(p), "v"(v) : "memory");
}
__device__ __forceinline__ void ntStore1(float* p, float v) {
    asm volatile("global_store_dword %0, %1, off nt sc1"
                 :: "v"(p), "v"(v) : "memory");
}

__global__ __launch_bounds__(NT)
void sch_kernel(const float* __restrict__ logits,
                const int* __restrict__ prev,
                float* __restrict__ out)
{
    const int g   = blockIdx.x;            // 0..511
    const int rA  = g;
    const int rB  = g + NBLK;
    const int s   = g % SS;                // rA%SS == rB%SS (512 % 64 == 0)
    const int bA  = rA / SS;
    const int bB  = rB / SS;
    const int tid = threadIdx.x;
    const float* rowA  = logits + (size_t)rA * VV;
    const float* rowB  = logits + (size_t)rB * VV;
    float*       orowA = out    + (size_t)rA * VV;
    float*       orowB = out    + (size_t)rB * VV;

    __shared__ uint32_t s_bm[BMW];
    __shared__ float    s_cv[CAP];    // row-A candidates (pre-temperature domain)
    __shared__ int      s_ci[CAP];
    __shared__ float    s_cv2[CAP];   // row-B candidates
    __shared__ int      s_ci2[CAP];
    __shared__ uint32_t s_hist[BINS];
    __shared__ uint32_t s_scan[16];   // 8 half-wave totals + 8 prefixes
    __shared__ int      s_ptok[PP];
    __shared__ int      s_pneg[PP];   // all_neg flag (same for both rows: same s)
    __shared__ float    s_prawA[PP];
    __shared__ float    s_prawB[PP];
    __shared__ float    s_ppenA[PP];
    __shared__ float    s_ppenB[PP];
    __shared__ float    s_binv[BCAP];
    __shared__ double   s_v64[KCAP];
    __shared__ double   s_e64[KCAP];
    __shared__ int      s_ki[KCAP];
    __shared__ float    s_kof[KCAP];
    __shared__ int      s_kiA[KCAP];  // saved row-A scatter list
    __shared__ float    s_kofA[KCAP];
    __shared__ int    s_cnt, s_cnt2, s_cntinv, s_b50, s_need, s_cntb, s_k50, s_kp, s_Kk;
    __shared__ int    s_hbar;         // half-barrier counter (monotone)
    __shared__ float  s_kth, s_rc;
    __shared__ double s_lse;

    // ---------------- phase 0: penalty setup, ONCE for both rows ----------------
    for (int i = tid; i < BMW; i += NT) s_bm[i] = 0u;
    if (tid < PP) s_pneg[tid] = 1;
    if (tid == 0) { s_cnt = 0; s_cnt2 = 0; s_cntinv = 0; s_hbar = 0; }
    __syncthreads();
    for (int pair = tid; pair < PP * BB; pair += NT) {
        int ti = pair & (PP - 1);
        int b2 = pair >> 6;
        int tok = prev[s * PP + ti];
        float gg = logits[((size_t)b2 * SS + s) * (size_t)VV + tok];
        if (gg >= 0.f) atomicAnd(&s_pneg[ti], 0);
        if (b2 == 0)  s_ptok[ti]  = tok;
        if (b2 == bA) s_prawA[ti] = gg;
        if (b2 == bB) s_prawB[ti] = gg;
    }
    __syncthreads();
    if (tid < PP) {
        int neg = s_pneg[tid];
        float ga = s_prawA[tid], gb = s_prawB[tid];
        s_ppenA[tid] = neg ? (ga * 1.2f) : (ga / 1.2f);
        s_ppenB[tid] = neg ? (gb * 1.2f) : (gb / 1.2f);
        int tok = s_ptok[tid];
        atomicOr(&s_bm[tok >> 5], 1u << (tok & 31));
    }
    __syncthreads();

    // ---------------- half-barrier (waves 0-7 only; spin on LDS) ----------------
    int hb_phase = 0;
    auto halfbar = [&]() {
        __threadfence_block();
        if ((tid & 63) == 0) atomicAdd(&s_hbar, 1);
        ++hb_phase;
        while (*(volatile int*)&s_hbar < 8 * hb_phase)
            __builtin_amdgcn_s_sleep(1);
        __threadfence_block();
    };

    // ---------------- generic helpers ----------------
    auto kbit = [&](int t) -> uint32_t {
        return (s_bm[t >> 5] >> (t & 31)) & 1u;
    };
    auto addRawP = [&](int t, float raw, float* cv, int* ci, int* pcnt) {
        if (raw >= TRAW) {
            int pos = atomicAdd(pcnt, 1);
            if (pos < CAP) { cv[pos] = raw; ci[pos] = t; }
        }
    };
    // barrier-free hot read stream, parameterized thread range [t0, nthr)
    auto streamFastP = [&](const float* row_, float* cv, int* ci, int* pcnt,
                           int t0, int nthr) {
        const int mis   = (int)(((size_t)row_ >> 2) & 3);
        const int head  = (4 - mis) & 3;
        const int nq    = (VV - head) >> 2;
        const int ttail = head + (nq << 2);
        const float4* p4 = reinterpret_cast<const float4*>(row_ + head);
        for (int t = t0; t < head; t += nthr) addRawP(t, row_[t], cv, ci, pcnt);
        int base = 0;
        for (; base + 4 * nthr <= nq; base += 4 * nthr) {
            float4 f[4];
            #pragma unroll
            for (int u = 0; u < 4; ++u) f[u] = p4[base + t0 + u * nthr];
            #pragma unroll
            for (int u = 0; u < 4; ++u) {
                int t = head + ((base + t0 + u * nthr) << 2);
                addRawP(t + 0, f[u].x, cv, ci, pcnt);
                addRawP(t + 1, f[u].y, cv, ci, pcnt);
                addRawP(t + 2, f[u].z, cv, ci, pcnt);
                addRawP(t + 3, f[u].w, cv, ci, pcnt);
            }
        }
        for (int q = base + t0; q < nq; q += nthr) {
            float4 f = p4[q];
            int t = head + (q << 2);
            addRawP(t + 0, f.x, cv, ci, pcnt);
            addRawP(t + 1, f.y, cv, ci, pcnt);
            addRawP(t + 2, f.z, cv, ci, pcnt);
            addRawP(t + 3, f.w, cv, ci, pcnt);
        }
        for (int t = ttail + t0; t < VV; t += nthr) addRawP(t, row_[t], cv, ci, pcnt);
    };
    // barrier-free nt+sc1 fill (no L3 allocation), parameterized thread range.
    // Ends with an explicit vmcnt(0) drain: compiler can't track asm stores.
    auto ntFill = [&](float* orow_, float rc_, int t0, int nthr) {
        const int omis   = (int)(((size_t)orow_ >> 2) & 3);
        const int ohead  = (4 - omis) & 3;
        const int onq    = (VV - ohead) >> 2;
        const int ottail = ohead + (onq << 2);
        float* obase = orow_ + ohead;
        f32x4 rc4; rc4.x = rc_; rc4.y = rc_; rc4.z = rc_; rc4.w = rc_;
        for (int t = t0; t < ohead; t += nthr) ntStore1(&orow_[t], rc_);
        for (int q = t0; q < onq; q += nthr)  ntStore4(obase + (q << 2), rc4);
        for (int t = ottail + t0; t < VV; t += nthr) ntStore1(&orow_[t], rc_);
        asm volatile("s_waitcnt vmcnt(0)" ::: "memory");
    };

    // ======== half-width (waves 0-7, halfbar-synced) mid-phase machinery ========
    auto procFullH = [&](int t, float raw, bool doHist, float thr, const float* ppenS,
                         float* cv, int* ci, int* pcnt) {
        float v = raw;
        if (kbit(t)) {
            #pragma unroll 1
            for (int j = 0; j < PP; ++j)
                if (s_ptok[j] == t) { v = ppenS[j]; break; }
        }
        if (!doHist) {
            if (v >= thr) {
                int pos = atomicAdd(pcnt, 1);
                if (pos < CAP) { cv[pos] = v; ci[pos] = t; }
            }
        } else {
            atomicAdd(&s_hist[fkey(v) >> 21], 1u);
        }
    };
    auto streamFullH = [&](bool doHist, float thr, const float* row_, const float* ppenS,
                           float* cv, int* ci, int* pcnt) {
        const int mis   = (int)(((size_t)row_ >> 2) & 3);
        const int head  = (4 - mis) & 3;
        const int nq    = (VV - head) >> 2;
        const int ttail = head + (nq << 2);
        const float4* p4 = reinterpret_cast<const float4*>(row_ + head);
        for (int t = tid; t < head; t += HNT) procFullH(t, row_[t], doHist, thr, ppenS, cv, ci, pcnt);
        for (int q = tid; q < nq; q += HNT) {
            float4 f = p4[q];
            int t = head + (q << 2);
            procFullH(t + 0, f.x, doHist, thr, ppenS, cv, ci, pcnt);
            procFullH(t + 1, f.y, doHist, thr, ppenS, cv, ci, pcnt);
            procFullH(t + 2, f.z, doHist, thr, ppenS, cv, ci, pcnt);
            procFullH(t + 3, f.w, doHist, thr, ppenS, cv, ci, pcnt);
        }
        for (int t = ttail + tid; t < VV; t += HNT) procFullH(t, row_[t], doHist, thr, ppenS, cv, ci, pcnt);
    };
    auto findB50H = [&](int target) {
        halfbar();                           // histogram complete
        const int per = BINS / HNT;          // 4 bins per thread
        int base = tid * per;
        uint32_t loc = 0;
        #pragma unroll
        for (int k2 = 0; k2 < per; ++k2) loc += s_hist[base + k2];
        uint32_t incl = loc;
        #pragma unroll
        for (int off = 1; off < 64; off <<= 1) {
            uint32_t u = (uint32_t)__shfl_up((int)incl, off, 64);
            if ((tid & 63) >= off) incl += u;
        }
        int wid = tid >> 6;                  // 0..7
        if ((tid & 63) == 63) s_scan[wid] = incl;
        halfbar();
        if (tid < 8) {
            uint32_t p = 0;
            for (int w = 0; w < tid; ++w) p += s_scan[w];
            s_scan[8 + tid] = p;
        }
        halfbar();
        uint32_t pre_incl = s_scan[8 + wid] + incl;
        uint32_t total    = s_scan[8 + 7] + s_scan[7];
        uint32_t run = total - pre_incl;
        for (int k2 = per - 1; k2 >= 0; --k2) {
            uint32_t h = s_hist[base + k2];
            uint32_t run2 = run + h;
            if (run < (uint32_t)target && run2 >= (uint32_t)target) {
                s_b50 = base + k2;
                s_need = target - (int)run;
            }
            run = run2;
        }
        halfbar();
    };
    auto doFallbackH = [&](const float* row_, const float* ppenS,
                           float* cv, int* ci, int* pcnt) {
        for (int i = tid; i < BINS; i += HNT) s_hist[i] = 0u;
        halfbar();
        streamFullH(true, 0.f, row_, ppenS, cv, ci, pcnt);
        findB50H(50);
        float thrF = key2f((uint32_t)s_b50 << 21);
        if (tid == 0) *pcnt = 0;
        halfbar();
        streamFullH(false, thrF, row_, ppenS, cv, ci, pcnt);
        halfbar();
    };
    auto computeKthH = [&](float* cv, int* pcnt) {
        for (int i = tid; i < BINS; i += HNT) s_hist[i] = 0u;
        if (tid == 0) { s_cntb = 0; s_kth = -FLT_MAX; }
        halfbar();
        int cc = min(*pcnt, CAP);
        for (int i = tid; i < cc; i += HNT)
            atomicAdd(&s_hist[fkey(cv[i]) >> 21], 1u);
        findB50H(50);
        int b50 = s_b50, need = s_need;
        for (int i = tid; i < cc; i += HNT) {
            if ((int)(fkey(cv[i]) >> 21) == b50) {
                int p = atomicAdd(&s_cntb, 1);
                if (p < BCAP) s_binv[p] = cv[i];
            }
        }
        halfbar();
        int cb = min(s_cntb, BCAP);
        for (int i = tid; i < cb; i += HNT) {
            float vi = s_binv[i];
            int gt = 0, ge = 0;
            for (int j = 0; j < cb; ++j) {
                float vj = s_binv[j];
                gt += (vj > vi);
                ge += (vj >= vi);
            }
            if (gt < need && ge >= need) s_kth = vi;   // benign race: same value
        }
        halfbar();
    };
    // mid phases on waves 0-7 (tid < HNT). Decision arithmetic identical to R3+.
    auto midPhasesH = [&](const float* row_, const float* prawS, const float* ppenS,
                          float* cv, int* ci, int* pcnt) {
        const int cntRaw = min(*pcnt, CAP);
        for (int i = tid; i < cntRaw; i += HNT) {
            if (kbit(ci[i])) {
                cv[i] = -FLT_MAX;
                atomicAdd(&s_cntinv, 1);
            }
        }
        halfbar();
        if (tid < PP) {
            int tok = s_ptok[tid];
            bool first = true;
            for (int j = 0; j < tid; ++j)
                if (s_ptok[j] == tok) { first = false; break; }
            if (first) {
                int pos = atomicAdd(pcnt, 1);
                if (pos < CAP) { cv[pos] = ppenS[tid]; ci[pos] = tok; }
            }
        }
        halfbar();
        bool fellback = false;
        {
            bool okc = (*pcnt <= CAP) && ((cntRaw - s_cntinv) >= 50);
            if (!okc) { doFallbackH(row_, ppenS, cv, ci, pcnt); fellback = true; }
        }
        computeKthH(cv, pcnt);
        if (!fellback && (s_kth - 1e-4f < TRAW)) {
            doFallbackH(row_, ppenS, cv, ci, pcnt);
            computeKthH(cv, pcnt);
        }
        if (tid == 0) s_k50 = 0;
        halfbar();
        const float gthr = s_kth - 1e-4f;
        const int cntc = min(*pcnt, CAP);
        for (int i = tid; i < cntc; i += HNT) {
            if (cv[i] >= gthr) {
                int p = atomicAdd(&s_k50, 1);
                if (p < KCAP) {
                    int tok = ci[i];
                    double v64;
                    if (kbit(tok)) {
                        int pj = 0;
                        #pragma unroll 1
                        for (int j = 0; j < PP; ++j)
                            if (s_ptok[j] == tok) { pj = j; break; }
                        double gd = (double)prawS[pj];
                        double pen = s_pneg[pj] ? (gd * 1.2) : (gd / 1.2);
                        v64 = pen / 0.8;
                    } else {
                        v64 = (double)cv[i] / 0.8;
                    }
                    s_v64[p] = v64;
                    s_ki[p]  = tok;
                }
            }
        }
        halfbar();
        const int k50c = min(s_k50, KCAP);
        for (int i = k50c + tid; i < KCAP; i += HNT) {
            s_v64[i] = -1e300;
            s_ki[i]  = (1 << 30) + i;
        }
        halfbar();
        // single-wave register bitonic sort (identical comparator)
        if (tid < 64) {
            int l = tid;
            double v0 = s_v64[l],    v1 = s_v64[l + 64];
            int    i0 = s_ki[l],     i1 = s_ki[l + 64];
            for (int k = 2; k <= KCAP; k <<= 1) {
                for (int j = k >> 1; j > 0; j >>= 1) {
                    if (j >= 64) {
                        bool before = (v0 > v1) || (v0 == v1 && i0 < i1);
                        if (!before) {
                            double tv = v0; v0 = v1; v1 = tv;
                            int    ti = i0; i0 = i1; i1 = ti;
                        }
                    } else {
                        double nv0 = __shfl_xor(v0, j, 64);
                        double nv1 = __shfl_xor(v1, j, 64);
                        int    ni0 = __shfl_xor(i0, j, 64);
                        int    ni1 = __shfl_xor(i1, j, 64);
                        bool lower = ((l & j) == 0);
                        bool up0 = ((l & k) == 0);
                        bool up1 = (((l + 64) & k) == 0);
                        bool bm0 = (v0 > nv0) || (v0 == nv0 && i0 < ni0);
                        bool bm1 = (v1 > nv1) || (v1 == nv1 && i1 < ni1);
                        bool keep0 = lower ? (up0 == bm0) : (up0 != bm0);
                        bool keep1 = lower ? (up1 == bm1) : (up1 != bm1);
                        if (!keep0) { v0 = nv0; i0 = ni0; }
                        if (!keep1) { v1 = nv1; i1 = ni1; }
                    }
                }
            }
            s_v64[l] = v0; s_v64[l + 64] = v1;
            s_ki[l]  = i0; s_ki[l + 64]  = i1;
        }
        halfbar();
        if (tid == 0) {
            int kk = k50c;
            int Kkept;
            if (kk <= 50) Kkept = kk;
            else {
                double kth64 = s_v64[49];
                Kkept = 50;
                while (Kkept < kk && s_v64[Kkept] == kth64) ++Kkept;
            }
            s_Kk = Kkept;
        }
        halfbar();
        const int Kk = s_Kk;
        const double mx = s_v64[0];
        if (tid < Kk) s_e64[tid] = exp(s_v64[tid] - mx);
        halfbar();
        if (tid == 0) {
            double D = 0.0;                    // same serial order as reference
            #pragma unroll 1
            for (int i = 0; i < Kk; ++i) D += s_e64[i];
            double c = 0.0;
            int Kp = 0;
            #pragma unroll 1
            for (int i = 0; i < Kk; ++i) {
                bool keep = (i == 0) || (c <= 0.9);
                c += s_e64[i] / D;
                if (keep) Kp = i + 1; else break;
            }
            double D2 = 0.0;
            #pragma unroll 1
            for (int i = 0; i < Kp; ++i) D2 += s_e64[i];
            double lse = log(D2);
            s_lse = lse;
            s_rc = (float)((-1e9 - mx) - lse);
            s_kp = Kp;
        }
        halfbar();
        if (tid < s_kp) s_kof[tid] = (float)((s_v64[tid] - mx) - s_lse);
        halfbar();
    };

    // ============================ schedule (R13, measured best) ============================
    // step 1: all waves read A
    streamFastP(rowA, s_cv, s_ci, &s_cnt, tid, NT);
    __syncthreads();

    // step 2: w0-7 mid-A  ∥  w8-15 read B (each crew owns a whole stream)
    if (tid < HNT) {
        midPhasesH(rowA, s_prawA, s_ppenA, s_cv, s_ci, &s_cnt);
    } else {
        streamFastP(rowB, s_cv2, s_ci2, &s_cnt2, tid - HNT, HNT);
    }
    __syncthreads();

    // step 3: save A results; reset for mid-B
    const float rcA = s_rc;
    const int   kpA = s_kp;
    if (tid < KCAP) { s_kiA[tid] = s_ki[tid]; s_kofA[tid] = s_kof[tid]; }
    if (tid == 0) s_cntinv = 0;
    __syncthreads();

    // step 4: w0-7 mid-B  ∥  w8-15 nt-fill A (whole row, single linear stream)
    if (tid < HNT) {
        midPhasesH(rowB, s_prawB, s_ppenB, s_cv2, s_ci2, &s_cnt2);
    } else {
        ntFill(orowA, rcA, tid - HNT, HNT);   // ends with vmcnt(0) drain
    }
    __syncthreads();   // fill-A complete before scatter

    // step 5: scatter A, then all waves fill B + scatter B
    if (tid < kpA) orowA[s_kiA[tid]] = s_kofA[tid];
    const float rcB = s_rc;
    ntFill(orowB, rcB, tid, NT);              // ends with vmcnt(0) drain
    __syncthreads();
    if (tid < s_kp) orowB[s_ki[tid]] = s_kof[tid];
}

extern "C" void kernel_launch(void* const* d_in, const int* in_sizes, int n_in,
                              void* d_out, int out_size, void* d_ws, size_t ws_size,
                              hipStream_t stream) {
    const float* logits = (const float*)d_in[0];
    const int*   prev   = (const int*)d_in[1];
    float*       out    = (float*)d_out;
    dim3 grid(NBLK), block(NT);
    hipLaunchKernelGGL(sch_kernel, grid, block, 0, stream, logits, prev, out);
}

// Round 20
// 89.910 us; speedup vs baseline: 1.9315x; 1.1894x over previous
//
#include <hip/hip_runtime.h>
#include <cstdint>
#include <cfloat>
#include <math.h>

// Problem constants (match reference)
#define BB 16
#define SS 64
#define VV 50257
#define PP 64

#define NT 1024         // threads per block (16 waves; 2 blocks/CU -> 32 waves/CU)
#define HNT 512         // half-block (waves 0-7) running the mid phases
#define NBLK 512        // block g handles rows g and g+512 (same s, same prev!)
#define BINS 2048       // key histogram bins (top 11 bits of ordered key)
#define CAP 1536        // candidate buffer capacity
#define BMW 1572        // bitmap words: ceil(50257/32)=1571 (+1 pad)
#define KCAP 128        // kept (top-k survivors) capacity
#define BCAP 512        // kth-bin member list capacity
#define TRAW 6.0f       // raw-domain candidate threshold (= 7.5 scaled * 0.8)

// FINAL FORM (R13, twice measured 89.99us). Design-space map:
//  - atomic/shfl in stream address path: -40% (R11)
//  - two crews splitting one row stream: -35% WRITE-inflation (R12/R15)
//  - non-8/8 crew geometry: regresses (R12/R15)
//  - producer/consumer block split: -93% (R17, half device idles)
//  - nt sc1 no-allocate fill: FETCH unchanged, -19% (R18) -> L3 theory dead
//  - plain __builtin_nontemporal_store fill: +14% (R7, kept)
//  - two-row pipeline w/ half-block crews + LDS spin barrier: +7% (R10, kept)

typedef float f32x4 __attribute__((ext_vector_type(4)));

// monotone float->uint key (increasing)
__device__ __forceinline__ uint32_t fkey(float f) {
    uint32_t u = __float_as_uint(f);
    return u ^ ((uint32_t)((int32_t)u >> 31) | 0x80000000u);
}
__device__ __forceinline__ float key2f(uint32_t u) {
    uint32_t b = (u & 0x80000000u) ? (u ^ 0x80000000u) : ~u;
    return __uint_as_float(b);
}

__global__ __launch_bounds__(NT)
void sch_kernel(const float* __restrict__ logits,
                const int* __restrict__ prev,
                float* __restrict__ out)
{
    const int g   = blockIdx.x;            // 0..511
    const int rA  = g;
    const int rB  = g + NBLK;
    const int s   = g % SS;                // rA%SS == rB%SS (512 % 64 == 0)
    const int bA  = rA / SS;
    const int bB  = rB / SS;
    const int tid = threadIdx.x;
    const float* rowA  = logits + (size_t)rA * VV;
    const float* rowB  = logits + (size_t)rB * VV;
    float*       orowA = out    + (size_t)rA * VV;
    float*       orowB = out    + (size_t)rB * VV;

    __shared__ uint32_t s_bm[BMW];
    __shared__ float    s_cv[CAP];    // row-A candidates (pre-temperature domain)
    __shared__ int      s_ci[CAP];
    __shared__ float    s_cv2[CAP];   // row-B candidates
    __shared__ int      s_ci2[CAP];
    __shared__ uint32_t s_hist[BINS];
    __shared__ uint32_t s_scan[16];   // 8 half-wave totals + 8 prefixes
    __shared__ int      s_ptok[PP];
    __shared__ int      s_pneg[PP];   // all_neg flag (same for both rows: same s)
    __shared__ float    s_prawA[PP];
    __shared__ float    s_prawB[PP];
    __shared__ float    s_ppenA[PP];
    __shared__ float    s_ppenB[PP];
    __shared__ float    s_binv[BCAP];
    __shared__ double   s_v64[KCAP];
    __shared__ double   s_e64[KCAP];
    __shared__ int      s_ki[KCAP];
    __shared__ float    s_kof[KCAP];
    __shared__ int      s_kiA[KCAP];  // saved row-A scatter list
    __shared__ float    s_kofA[KCAP];
    __shared__ int    s_cnt, s_cnt2, s_cntinv, s_b50, s_need, s_cntb, s_k50, s_kp, s_Kk;
    __shared__ int    s_hbar;         // half-barrier counter (monotone)
    __shared__ float  s_kth, s_rc;
    __shared__ double s_lse;

    // ---------------- phase 0: penalty setup, ONCE for both rows ----------------
    for (int i = tid; i < BMW; i += NT) s_bm[i] = 0u;
    if (tid < PP) s_pneg[tid] = 1;
    if (tid == 0) { s_cnt = 0; s_cnt2 = 0; s_cntinv = 0; s_hbar = 0; }
    __syncthreads();
    for (int pair = tid; pair < PP * BB; pair += NT) {
        int ti = pair & (PP - 1);
        int b2 = pair >> 6;
        int tok = prev[s * PP + ti];
        float gg = logits[((size_t)b2 * SS + s) * (size_t)VV + tok];
        if (gg >= 0.f) atomicAnd(&s_pneg[ti], 0);
        if (b2 == 0)  s_ptok[ti]  = tok;
        if (b2 == bA) s_prawA[ti] = gg;
        if (b2 == bB) s_prawB[ti] = gg;
    }
    __syncthreads();
    if (tid < PP) {
        int neg = s_pneg[tid];
        float ga = s_prawA[tid], gb = s_prawB[tid];
        s_ppenA[tid] = neg ? (ga * 1.2f) : (ga / 1.2f);
        s_ppenB[tid] = neg ? (gb * 1.2f) : (gb / 1.2f);
        int tok = s_ptok[tid];
        atomicOr(&s_bm[tok >> 5], 1u << (tok & 31));
    }
    __syncthreads();

    // ---------------- half-barrier (waves 0-7 only; spin on LDS) ----------------
    int hb_phase = 0;
    auto halfbar = [&]() {
        __threadfence_block();
        if ((tid & 63) == 0) atomicAdd(&s_hbar, 1);
        ++hb_phase;
        while (*(volatile int*)&s_hbar < 8 * hb_phase)
            __builtin_amdgcn_s_sleep(1);
        __threadfence_block();
    };

    // ---------------- generic helpers ----------------
    auto kbit = [&](int t) -> uint32_t {
        return (s_bm[t >> 5] >> (t & 31)) & 1u;
    };
    auto addRawP = [&](int t, float raw, float* cv, int* ci, int* pcnt) {
        if (raw >= TRAW) {
            int pos = atomicAdd(pcnt, 1);
            if (pos < CAP) { cv[pos] = raw; ci[pos] = t; }
        }
    };
    // barrier-free hot read stream, parameterized thread range [t0, nthr)
    auto streamFastP = [&](const float* row_, float* cv, int* ci, int* pcnt,
                           int t0, int nthr) {
        const int mis   = (int)(((size_t)row_ >> 2) & 3);
        const int head  = (4 - mis) & 3;
        const int nq    = (VV - head) >> 2;
        const int ttail = head + (nq << 2);
        const float4* p4 = reinterpret_cast<const float4*>(row_ + head);
        for (int t = t0; t < head; t += nthr) addRawP(t, row_[t], cv, ci, pcnt);
        int base = 0;
        for (; base + 4 * nthr <= nq; base += 4 * nthr) {
            float4 f[4];
            #pragma unroll
            for (int u = 0; u < 4; ++u) f[u] = p4[base + t0 + u * nthr];
            #pragma unroll
            for (int u = 0; u < 4; ++u) {
                int t = head + ((base + t0 + u * nthr) << 2);
                addRawP(t + 0, f[u].x, cv, ci, pcnt);
                addRawP(t + 1, f[u].y, cv, ci, pcnt);
                addRawP(t + 2, f[u].z, cv, ci, pcnt);
                addRawP(t + 3, f[u].w, cv, ci, pcnt);
            }
        }
        for (int q = base + t0; q < nq; q += nthr) {
            float4 f = p4[q];
            int t = head + (q << 2);
            addRawP(t + 0, f.x, cv, ci, pcnt);
            addRawP(t + 1, f.y, cv, ci, pcnt);
            addRawP(t + 2, f.z, cv, ci, pcnt);
            addRawP(t + 3, f.w, cv, ci, pcnt);
        }
        for (int t = ttail + t0; t < VV; t += nthr) addRawP(t, row_[t], cv, ci, pcnt);
    };
    // barrier-free nt fill, parameterized thread range
    auto ntFill = [&](float* orow_, float rc_, int t0, int nthr) {
        const int omis   = (int)(((size_t)orow_ >> 2) & 3);
        const int ohead  = (4 - omis) & 3;
        const int onq    = (VV - ohead) >> 2;
        const int ottail = ohead + (onq << 2);
        f32x4* o4 = reinterpret_cast<f32x4*>(orow_ + ohead);
        f32x4 rc4; rc4.x = rc_; rc4.y = rc_; rc4.z = rc_; rc4.w = rc_;
        for (int t = t0; t < ohead; t += nthr)
            __builtin_nontemporal_store(rc_, &orow_[t]);
        for (int q = t0; q < onq; q += nthr)
            __builtin_nontemporal_store(rc4, &o4[q]);
        for (int t = ottail + t0; t < VV; t += nthr)
            __builtin_nontemporal_store(rc_, &orow_[t]);
    };

    // ======== half-width (waves 0-7, halfbar-synced) mid-phase machinery ========
    auto procFullH = [&](int t, float raw, bool doHist, float thr, const float* ppenS,
                         float* cv, int* ci, int* pcnt) {
        float v = raw;
        if (kbit(t)) {
            #pragma unroll 1
            for (int j = 0; j < PP; ++j)
                if (s_ptok[j] == t) { v = ppenS[j]; break; }
        }
        if (!doHist) {
            if (v >= thr) {
                int pos = atomicAdd(pcnt, 1);
                if (pos < CAP) { cv[pos] = v; ci[pos] = t; }
            }
        } else {
            atomicAdd(&s_hist[fkey(v) >> 21], 1u);
        }
    };
    auto streamFullH = [&](bool doHist, float thr, const float* row_, const float* ppenS,
                           float* cv, int* ci, int* pcnt) {
        const int mis   = (int)(((size_t)row_ >> 2) & 3);
        const int head  = (4 - mis) & 3;
        const int nq    = (VV - head) >> 2;
        const int ttail = head + (nq << 2);
        const float4* p4 = reinterpret_cast<const float4*>(row_ + head);
        for (int t = tid; t < head; t += HNT) procFullH(t, row_[t], doHist, thr, ppenS, cv, ci, pcnt);
        for (int q = tid; q < nq; q += HNT) {
            float4 f = p4[q];
            int t = head + (q << 2);
            procFullH(t + 0, f.x, doHist, thr, ppenS, cv, ci, pcnt);
            procFullH(t + 1, f.y, doHist, thr, ppenS, cv, ci, pcnt);
            procFullH(t + 2, f.z, doHist, thr, ppenS, cv, ci, pcnt);
            procFullH(t + 3, f.w, doHist, thr, ppenS, cv, ci, pcnt);
        }
        for (int t = ttail + tid; t < VV; t += HNT) procFullH(t, row_[t], doHist, thr, ppenS, cv, ci, pcnt);
    };
    auto findB50H = [&](int target) {
        halfbar();                           // histogram complete
        const int per = BINS / HNT;          // 4 bins per thread
        int base = tid * per;
        uint32_t loc = 0;
        #pragma unroll
        for (int k2 = 0; k2 < per; ++k2) loc += s_hist[base + k2];
        uint32_t incl = loc;
        #pragma unroll
        for (int off = 1; off < 64; off <<= 1) {
            uint32_t u = (uint32_t)__shfl_up((int)incl, off, 64);
            if ((tid & 63) >= off) incl += u;
        }
        int wid = tid >> 6;                  // 0..7
        if ((tid & 63) == 63) s_scan[wid] = incl;
        halfbar();
        if (tid < 8) {
            uint32_t p = 0;
            for (int w = 0; w < tid; ++w) p += s_scan[w];
            s_scan[8 + tid] = p;
        }
        halfbar();
        uint32_t pre_incl = s_scan[8 + wid] + incl;
        uint32_t total    = s_scan[8 + 7] + s_scan[7];
        uint32_t run = total - pre_incl;
        for (int k2 = per - 1; k2 >= 0; --k2) {
            uint32_t h = s_hist[base + k2];
            uint32_t run2 = run + h;
            if (run < (uint32_t)target && run2 >= (uint32_t)target) {
                s_b50 = base + k2;
                s_need = target - (int)run;
            }
            run = run2;
        }
        halfbar();
    };
    auto doFallbackH = [&](const float* row_, const float* ppenS,
                           float* cv, int* ci, int* pcnt) {
        for (int i = tid; i < BINS; i += HNT) s_hist[i] = 0u;
        halfbar();
        streamFullH(true, 0.f, row_, ppenS, cv, ci, pcnt);
        findB50H(50);
        float thrF = key2f((uint32_t)s_b50 << 21);
        if (tid == 0) *pcnt = 0;
        halfbar();
        streamFullH(false, thrF, row_, ppenS, cv, ci, pcnt);
        halfbar();
    };
    auto computeKthH = [&](float* cv, int* pcnt) {
        for (int i = tid; i < BINS; i += HNT) s_hist[i] = 0u;
        if (tid == 0) { s_cntb = 0; s_kth = -FLT_MAX; }
        halfbar();
        int cc = min(*pcnt, CAP);
        for (int i = tid; i < cc; i += HNT)
            atomicAdd(&s_hist[fkey(cv[i]) >> 21], 1u);
        findB50H(50);
        int b50 = s_b50, need = s_need;
        for (int i = tid; i < cc; i += HNT) {
            if ((int)(fkey(cv[i]) >> 21) == b50) {
                int p = atomicAdd(&s_cntb, 1);
                if (p < BCAP) s_binv[p] = cv[i];
            }
        }
        halfbar();
        int cb = min(s_cntb, BCAP);
        for (int i = tid; i < cb; i += HNT) {
            float vi = s_binv[i];
            int gt = 0, ge = 0;
            for (int j = 0; j < cb; ++j) {
                float vj = s_binv[j];
                gt += (vj > vi);
                ge += (vj >= vi);
            }
            if (gt < need && ge >= need) s_kth = vi;   // benign race: same value
        }
        halfbar();
    };
    // mid phases on waves 0-7 (tid < HNT). Decision arithmetic identical to R3+.
    auto midPhasesH = [&](const float* row_, const float* prawS, const float* ppenS,
                          float* cv, int* ci, int* pcnt) {
        const int cntRaw = min(*pcnt, CAP);
        for (int i = tid; i < cntRaw; i += HNT) {
            if (kbit(ci[i])) {
                cv[i] = -FLT_MAX;
                atomicAdd(&s_cntinv, 1);
            }
        }
        halfbar();
        if (tid < PP) {
            int tok = s_ptok[tid];
            bool first = true;
            for (int j = 0; j < tid; ++j)
                if (s_ptok[j] == tok) { first = false; break; }
            if (first) {
                int pos = atomicAdd(pcnt, 1);
                if (pos < CAP) { cv[pos] = ppenS[tid]; ci[pos] = tok; }
            }
        }
        halfbar();
        bool fellback = false;
        {
            bool okc = (*pcnt <= CAP) && ((cntRaw - s_cntinv) >= 50);
            if (!okc) { doFallbackH(row_, ppenS, cv, ci, pcnt); fellback = true; }
        }
        computeKthH(cv, pcnt);
        if (!fellback && (s_kth - 1e-4f < TRAW)) {
            doFallbackH(row_, ppenS, cv, ci, pcnt);
            computeKthH(cv, pcnt);
        }
        if (tid == 0) s_k50 = 0;
        halfbar();
        const float gthr = s_kth - 1e-4f;
        const int cntc = min(*pcnt, CAP);
        for (int i = tid; i < cntc; i += HNT) {
            if (cv[i] >= gthr) {
                int p = atomicAdd(&s_k50, 1);
                if (p < KCAP) {
                    int tok = ci[i];
                    double v64;
                    if (kbit(tok)) {
                        int pj = 0;
                        #pragma unroll 1
                        for (int j = 0; j < PP; ++j)
                            if (s_ptok[j] == tok) { pj = j; break; }
                        double gd = (double)prawS[pj];
                        double pen = s_pneg[pj] ? (gd * 1.2) : (gd / 1.2);
                        v64 = pen / 0.8;
                    } else {
                        v64 = (double)cv[i] / 0.8;
                    }
                    s_v64[p] = v64;
                    s_ki[p]  = tok;
                }
            }
        }
        halfbar();
        const int k50c = min(s_k50, KCAP);
        for (int i = k50c + tid; i < KCAP; i += HNT) {
            s_v64[i] = -1e300;
            s_ki[i]  = (1 << 30) + i;
        }
        halfbar();
        // single-wave register bitonic sort (identical comparator)
        if (tid < 64) {
            int l = tid;
            double v0 = s_v64[l],    v1 = s_v64[l + 64];
            int    i0 = s_ki[l],     i1 = s_ki[l + 64];
            for (int k = 2; k <= KCAP; k <<= 1) {
                for (int j = k >> 1; j > 0; j >>= 1) {
                    if (j >= 64) {
                        bool before = (v0 > v1) || (v0 == v1 && i0 < i1);
                        if (!before) {
                            double tv = v0; v0 = v1; v1 = tv;
                            int    ti = i0; i0 = i1; i1 = ti;
                        }
                    } else {
                        double nv0 = __shfl_xor(v0, j, 64);
                        double nv1 = __shfl_xor(v1, j, 64);
                        int    ni0 = __shfl_xor(i0, j, 64);
                        int    ni1 = __shfl_xor(i1, j, 64);
                        bool lower = ((l & j) == 0);
                        bool up0 = ((l & k) == 0);
                        bool up1 = (((l + 64) & k) == 0);
                        bool bm0 = (v0 > nv0) || (v0 == nv0 && i0 < ni0);
                        bool bm1 = (v1 > nv1) || (v1 == nv1 && i1 < ni1);
                        bool keep0 = lower ? (up0 == bm0) : (up0 != bm0);
                        bool keep1 = lower ? (up1 == bm1) : (up1 != bm1);
                        if (!keep0) { v0 = nv0; i0 = ni0; }
                        if (!keep1) { v1 = nv1; i1 = ni1; }
                    }
                }
            }
            s_v64[l] = v0; s_v64[l + 64] = v1;
            s_ki[l]  = i0; s_ki[l + 64]  = i1;
        }
        halfbar();
        if (tid == 0) {
            int kk = k50c;
            int Kkept;
            if (kk <= 50) Kkept = kk;
            else {
                double kth64 = s_v64[49];
                Kkept = 50;
                while (Kkept < kk && s_v64[Kkept] == kth64) ++Kkept;
            }
            s_Kk = Kkept;
        }
        halfbar();
        const int Kk = s_Kk;
        const double mx = s_v64[0];
        if (tid < Kk) s_e64[tid] = exp(s_v64[tid] - mx);
        halfbar();
        if (tid == 0) {
            double D = 0.0;                    // same serial order as reference
            #pragma unroll 1
            for (int i = 0; i < Kk; ++i) D += s_e64[i];
            double c = 0.0;
            int Kp = 0;
            #pragma unroll 1
            for (int i = 0; i < Kk; ++i) {
                bool keep = (i == 0) || (c <= 0.9);
                c += s_e64[i] / D;
                if (keep) Kp = i + 1; else break;
            }
            double D2 = 0.0;
            #pragma unroll 1
            for (int i = 0; i < Kp; ++i) D2 += s_e64[i];
            double lse = log(D2);
            s_lse = lse;
            s_rc = (float)((-1e9 - mx) - lse);
            s_kp = Kp;
        }
        halfbar();
        if (tid < s_kp) s_kof[tid] = (float)((s_v64[tid] - mx) - s_lse);
        halfbar();
    };

    // ============================ schedule (R13, measured best) ============================
    // step 1: all waves read A
    streamFastP(rowA, s_cv, s_ci, &s_cnt, tid, NT);
    __syncthreads();

    // step 2: w0-7 mid-A  ∥  w8-15 read B (each crew owns a whole stream)
    if (tid < HNT) {
        midPhasesH(rowA, s_prawA, s_ppenA, s_cv, s_ci, &s_cnt);
    } else {
        streamFastP(rowB, s_cv2, s_ci2, &s_cnt2, tid - HNT, HNT);
    }
    __syncthreads();

    // step 3: save A results; reset for mid-B
    const float rcA = s_rc;
    const int   kpA = s_kp;
    if (tid < KCAP) { s_kiA[tid] = s_ki[tid]; s_kofA[tid] = s_kof[tid]; }
    if (tid == 0) s_cntinv = 0;
    __syncthreads();

    // step 4: w0-7 mid-B  ∥  w8-15 nt-fill A (whole row, single linear stream)
    if (tid < HNT) {
        midPhasesH(rowB, s_prawB, s_ppenB, s_cv2, s_ci2, &s_cnt2);
    } else {
        ntFill(orowA, rcA, tid - HNT, HNT);
    }
    __syncthreads();   // each wave drains its own vmcnt before s_barrier -> fill-A done

    // step 5: scatter A, then all waves fill B + scatter B
    if (tid < kpA) orowA[s_kiA[tid]] = s_kofA[tid];
    const float rcB = s_rc;
    ntFill(orowB, rcB, tid, NT);
    __syncthreads();   // drain fill-B before scatter
    if (tid < s_kp) orowB[s_ki[tid]] = s_kof[tid];
}

extern "C" void kernel_launch(void* const* d_in, const int* in_sizes, int n_in,
                              void* d_out, int out_size, void* d_ws, size_t ws_size,
                              hipStream_t stream) {
    const float* logits = (const float*)d_in[0];
    const int*   prev   = (const int*)d_in[1];
    float*       out    = (float*)d_out;
    dim3 grid(NBLK), block(NT);
    hipLaunchKernelGGL(sch_kernel, grid, block, 0, stream, logits, prev, out);
}